// Round 5
// baseline (11322.135 us; speedup 1.0000x reference)
//
#include <hip/hip_runtime.h>
#include <math.h>

#define TT 2048
#define NB 64
#define EE 256
#define HH 256
#define NGRP 16   // batch groups (4 batches each)
#define PJ 16     // j-partitions (WGs) per group
#define JW 16     // j per WG
#define ROWS 64   // gate-rows per WG (4 gates x JW)
#define LDW 260   // padded LDS row stride in floats

__device__ __forceinline__ float sigf(float x) { return 1.f / (1.f + expf(-x)); }

__device__ __forceinline__ unsigned long long packh(unsigned tag, float v) {
    union { float f; unsigned u; } c; c.f = v;
    return ((unsigned long long)tag << 32) | (unsigned long long)c.u;
}

// Persistent grouped LSTM: 256 WGs = 16 batch-groups x 16 j-slices, 1 WG/CU.
// Handshake: 64-bit relaxed agent atomics {tag=t+1, f32 h}, double-buffered
// by parity. R5: (a) only 64 canary threads spin (one per 128B producer
// line); all data loads still tag-verified, so canary is purely a poll-
// concentration heuristic. (b) W_hh rows live in VGPRs (1 wave/SIMD -> 512
// VGPR budget); hacc is register-fed, off the LDS-issue bottleneck.
__global__ __launch_bounds__(256, 1)
void lstm_kernel(const int* __restrict__ sent, const float* __restrict__ emb,
                 const float* __restrict__ W_ih, const float* __restrict__ W_hh,
                 const float* __restrict__ b_ih, const float* __restrict__ b_hh,
                 const float* __restrict__ W_z,
                 unsigned long long* __restrict__ hbuf,
                 float* __restrict__ part)
{
    __shared__ float Wih_s[ROWS][LDW];
    __shared__ float Whh_s[ROWS][LDW];
    __shared__ float x_s[4][LDW];
    __shared__ float h_s[4][LDW];
    __shared__ float g_s[4][4][JW];   // [gate][b][jj]
    __shared__ float c_s[4][JW];
    __shared__ float p_s[4][JW];
    __shared__ int   tok_ns[4];

    const int tid  = threadIdx.x;
    const int grp  = blockIdx.x >> 4;     // 0..15 batch group
    const int jgrp = blockIdx.x & 15;     // 0..15 j-slice
    const int b0   = grp << 2;
    const int j0   = jgrp << 4;

    const int wv   = tid >> 6;            // 0..3 == gate index
    const int lane = tid & 63;
    const int rr   = lane >> 2;           // 0..15
    const int bl   = lane & 3;            // 0..3
    const int lr   = (wv << 4) + rr;      // 0..63 local row
    const int rg   = wv * HH + j0 + rr;   // global gate row

    // Load W slices once (persistent). Row layout: lr = gate*16 + jj.
    for (int i = tid; i < ROWS * (EE / 4); i += 256) {
        int row = i >> 6;                 // 64 float4 per row
        int c4  = i & 63;
        int gate = row >> 4, jj = row & 15;
        int grow = gate * HH + j0 + jj;
        float4 wih = ((const float4*)(W_ih + (long)grow * EE))[c4];
        float4 whh = ((const float4*)(W_hh + (long)grow * EE))[c4];
        ((float4*)&Wih_s[row][0])[c4] = wih;
        ((float4*)&Whh_s[row][0])[c4] = whh;
    }
    const float bias_r = b_ih[rg] + b_hh[rg];
    float wz_r = 0.f;
    if (tid < 64) {
        c_s[tid >> 4][tid & 15] = 0.f;
        wz_r = W_z[j0 + (tid & 15)];
    }
    if (tid < 4) tok_ns[tid] = sent[0 * NB + b0 + tid];
    __syncthreads();

    // Copy this thread's W_hh row into registers (64 float4 = 256 VGPRs).
    float4 whh_r[EE / 4];
    #pragma unroll
    for (int k4 = 0; k4 < EE / 4; ++k4)
        whh_r[k4] = *((const float4*)&Whh_s[lr][k4 * 4]);

    {   // prologue: x_s for t=0
        int b  = tid >> 6;
        int e4 = tid & 63;
        float4 xv = ((const float4*)(emb + (long)tok_ns[b] * EE))[e4];
        ((float4*)&x_s[b][0])[e4] = xv;
    }
    __syncthreads();

    // consumer data mapping: this thread loads h[(b0+cb)][cj..cj+3]
    const int cb = tid >> 6;
    const int cj = (tid & 63) << 2;
    // canary mapping (tid<64): spin on producer p's line for batch kb:
    // slot (b0+kb)*HH + 16p+15  (last slot of that 128B line)
    const int kb = tid >> 4;              // 0..3
    const int kp = tid & 15;              // 0..15 producer

    for (int t = 0; t < TT; ++t) {
        // ---- phase 1: x-projection (x_s ready from previous iteration) ----
        float4 ax0 = make_float4(0.f, 0.f, 0.f, 0.f);
        float4 ax1 = make_float4(0.f, 0.f, 0.f, 0.f);
        #pragma unroll 8
        for (int k8 = 0; k8 < EE / 8; ++k8) {
            float4 w0 = *((const float4*)&Wih_s[lr][k8 * 8]);
            float4 w1 = *((const float4*)&Wih_s[lr][k8 * 8 + 4]);
            float4 x0 = *((const float4*)&x_s[bl][k8 * 8]);
            float4 x1 = *((const float4*)&x_s[bl][k8 * 8 + 4]);
            ax0.x += w0.x * x0.x; ax0.y += w0.y * x0.y;
            ax0.z += w0.z * x0.z; ax0.w += w0.w * x0.w;
            ax1.x += w1.x * x1.x; ax1.y += w1.y * x1.y;
            ax1.z += w1.z * x1.z; ax1.w += w1.w * x1.w;
        }
        float pre = bias_r + (((ax0.x + ax0.y) + (ax0.z + ax0.w)) +
                              (((ax1.x + ax1.y) + (ax1.z + ax1.w))));

        const bool pf = (t + 1 < TT);
        if (tid < 4 && pf) tok_ns[tid] = sent[(t + 1) * NB + b0 + tid];

        // ---- phase 2a: canary spin (64 threads), then bulk tagged loads ----
        const unsigned want = (unsigned)t;          // h_{t-1} carries tag t
        const size_t parbase = (size_t)(((t - 1) & 1) * NB) * HH;
        if (t > 0 && tid < 64) {
            unsigned long long* cp =
                hbuf + parbase + (size_t)(b0 + kb) * HH + (kp << 4) + 15;
            while ((unsigned)(__hip_atomic_load(cp, __ATOMIC_RELAXED,
                        __HIP_MEMORY_SCOPE_AGENT) >> 32) != want) { }
        }
        __syncthreads();   // B1: every producer line observed in MALL

        if (t > 0) {
            unsigned long long* hp =
                hbuf + parbase + (size_t)(b0 + cb) * HH + cj;
            unsigned long long v0, v1, v2, v3;
            v0 = __hip_atomic_load(hp + 0, __ATOMIC_RELAXED, __HIP_MEMORY_SCOPE_AGENT);
            v1 = __hip_atomic_load(hp + 1, __ATOMIC_RELAXED, __HIP_MEMORY_SCOPE_AGENT);
            v2 = __hip_atomic_load(hp + 2, __ATOMIC_RELAXED, __HIP_MEMORY_SCOPE_AGENT);
            v3 = __hip_atomic_load(hp + 3, __ATOMIC_RELAXED, __HIP_MEMORY_SCOPE_AGENT);
            while ((unsigned)(v0 >> 32) != want)   // hard correctness backstop
                v0 = __hip_atomic_load(hp + 0, __ATOMIC_RELAXED, __HIP_MEMORY_SCOPE_AGENT);
            while ((unsigned)(v1 >> 32) != want)
                v1 = __hip_atomic_load(hp + 1, __ATOMIC_RELAXED, __HIP_MEMORY_SCOPE_AGENT);
            while ((unsigned)(v2 >> 32) != want)
                v2 = __hip_atomic_load(hp + 2, __ATOMIC_RELAXED, __HIP_MEMORY_SCOPE_AGENT);
            while ((unsigned)(v3 >> 32) != want)
                v3 = __hip_atomic_load(hp + 3, __ATOMIC_RELAXED, __HIP_MEMORY_SCOPE_AGENT);
            union { unsigned u; float f; } c0, c1, c2, c3;
            c0.u = (unsigned)v0; c1.u = (unsigned)v1;
            c2.u = (unsigned)v2; c3.u = (unsigned)v3;
            h_s[cb][cj + 0] = c0.f; h_s[cb][cj + 1] = c1.f;
            h_s[cb][cj + 2] = c2.f; h_s[cb][cj + 3] = c3.f;
        }
        __syncthreads();   // B1b: h_s ready

        // prefetch next emb row into registers (off critical path)
        float4 xv;
        if (pf) {
            int b  = tid >> 6;
            int e4 = tid & 63;
            xv = ((const float4*)(emb + (long)tok_ns[b] * EE))[e4];
        }

        // ---- phase 2b: recurrent projection (register-fed W_hh) ----
        if (t > 0) {
            float4 ah0 = make_float4(0.f, 0.f, 0.f, 0.f);
            float4 ah1 = make_float4(0.f, 0.f, 0.f, 0.f);
            #pragma unroll
            for (int k8 = 0; k8 < HH / 8; ++k8) {
                float4 w0 = whh_r[2 * k8];
                float4 w1 = whh_r[2 * k8 + 1];
                float4 h0 = *((const float4*)&h_s[bl][k8 * 8]);
                float4 h1 = *((const float4*)&h_s[bl][k8 * 8 + 4]);
                ah0.x += w0.x * h0.x; ah0.y += w0.y * h0.y;
                ah0.z += w0.z * h0.z; ah0.w += w0.w * h0.w;
                ah1.x += w1.x * h1.x; ah1.y += w1.y * h1.y;
                ah1.z += w1.z * h1.z; ah1.w += w1.w * h1.w;
            }
            pre += (((ah0.x + ah0.y) + (ah0.z + ah0.w)) +
                    ((ah1.x + ah1.y) + (ah1.z + ah1.w)));
        }
        g_s[wv][bl][rr] = pre;
        __syncthreads();   // B2: g_s ready

        // ---- phase 3: gates + state update + tagged publish ----
        if (tid < 64) {
            int b = tid >> 4, jj = tid & 15;
            float gi = g_s[0][b][jj], gf = g_s[1][b][jj];
            float gg = g_s[2][b][jj], go = g_s[3][b][jj];
            float c  = c_s[b][jj];
            float cn = sigf(gf) * c + sigf(gi) * tanhf(gg);
            float hn = sigf(go) * tanhf(cn);
            c_s[b][jj] = cn;
            p_s[b][jj] = hn * wz_r;
            __hip_atomic_store(
                hbuf + ((size_t)((t & 1) * NB + b0 + b)) * HH + j0 + jj,
                packh((unsigned)(t + 1), hn),
                __ATOMIC_RELAXED, __HIP_MEMORY_SCOPE_AGENT);
        }
        __syncthreads();   // B3: p_s ready; x_s reads done

        if (tid < 4) {     // deterministic pz partial for this (t, jslice, b)
            float s = 0.f;
            #pragma unroll
            for (int jj = 0; jj < JW; ++jj) s += p_s[tid][jj];
            part[(t * PJ + jgrp) * NB + b0 + tid] = s;
        }
        if (pf) {          // stage next x into LDS
            int b  = tid >> 6;
            int e4 = tid & 63;
            ((float4*)&x_s[b][0])[e4] = xv;
        }
        __syncthreads();   // B4: x_s ready for next iteration
    }
}

__global__ void pz_kernel(const float* __restrict__ part,
                          const float* __restrict__ noise,
                          const float* __restrict__ b_z,
                          float* __restrict__ out)
{
    int idx = blockIdx.x * blockDim.x + threadIdx.x;  // t*64 + b
    if (idx >= TT * NB) return;
    int t = idx >> 6, b = idx & 63;
    float s = b_z[0];
    #pragma unroll
    for (int jg = 0; jg < PJ; ++jg) s += part[(t * PJ + jg) * NB + b];
    float pz = 1.f / (1.f + expf(-s));
    out[idx] = pz;
    out[TT * NB + idx] = (noise[idx] < pz) ? 1.f : 0.f;
}

// One block per batch column: stable compaction of tokens where z==1.
__global__ void compact_kernel(const int* __restrict__ sent,
                               const float* __restrict__ zbuf,
                               float* __restrict__ rat,
                               float* __restrict__ zsz)
{
    __shared__ float rat_s[TT];
    __shared__ int scan_s[256];
    int b = blockIdx.x, tid = threadIdx.x;
    int zloc[8];
    int base = tid * 8;
    int c = 0;
    #pragma unroll
    for (int i = 0; i < 8; ++i) {
        zloc[i] = (zbuf[(base + i) * NB + b] != 0.f) ? 1 : 0;
        c += zloc[i];
    }
    scan_s[tid] = c;
    for (int i = tid; i < TT; i += 256) rat_s[i] = 0.f;
    __syncthreads();
    for (int off = 1; off < 256; off <<= 1) {
        int v = scan_s[tid];
        int add = (tid >= off) ? scan_s[tid - off] : 0;
        __syncthreads();
        scan_s[tid] = v + add;
        __syncthreads();
    }
    int total = scan_s[255];
    int pos = scan_s[tid] - c;  // exclusive prefix
    #pragma unroll
    for (int i = 0; i < 8; ++i) {
        if (zloc[i]) { rat_s[pos] = (float)sent[(base + i) * NB + b]; ++pos; }
    }
    __syncthreads();
    for (int i = tid; i < TT; i += 256) rat[i * NB + b] = rat_s[i];
    if (tid == 0) zsz[b] = (float)total;
}

extern "C" void kernel_launch(void* const* d_in, const int* in_sizes, int n_in,
                              void* d_out, int out_size, void* d_ws, size_t ws_size,
                              hipStream_t stream)
{
    const int*   sent  = (const int*)d_in[0];
    const float* noise = (const float*)d_in[1];
    const float* emb   = (const float*)d_in[2];
    const float* W_ih  = (const float*)d_in[3];
    const float* W_hh  = (const float*)d_in[4];
    const float* b_ih  = (const float*)d_in[5];
    const float* b_hh  = (const float*)d_in[6];
    const float* W_z   = (const float*)d_in[7];
    const float* b_z   = (const float*)d_in[8];
    float* out = (float*)d_out;

    char* ws = (char*)d_ws;
    unsigned long long* hbuf = (unsigned long long*)ws;     // 2*64*256*8 = 256 KB
    float* part = (float*)(ws + 262144);                    // 2048*16*64*4 = 8 MB

    // tags must start != any expected tag (1..2048)
    hipMemsetAsync(hbuf, 0, 2 * NB * HH * sizeof(unsigned long long), stream);

    lstm_kernel<<<256, 256, 0, stream>>>(sent, emb, W_ih, W_hh, b_ih, b_hh, W_z,
                                         hbuf, part);
    pz_kernel<<<(TT * NB) / 256, 256, 0, stream>>>(part, noise, b_z, out);
    compact_kernel<<<NB, 256, 0, stream>>>(sent, out + TT * NB,
                                           out + 2 * TT * NB, out + 3 * TT * NB);
}

// Round 6
// 6035.298 us; speedup vs baseline: 1.8760x; 1.8760x over previous
//
#include <hip/hip_runtime.h>
#include <math.h>

#define TT 2048
#define NB 64
#define EE 256
#define HH 256
#define NGRP 16   // batch groups (4 batches each)
#define PJ 16     // j-partitions (WGs) per group
#define JW 16     // j per WG
#define XLD 288   // swizzled row: 256 + 4 pad per 32 floats
// swizzled index: phys(k) = k + (k>>5)*4  -> kc chunks land on distinct banks

__device__ __forceinline__ float sigf(float x) { return 1.f / (1.f + expf(-x)); }

__device__ __forceinline__ unsigned long long packh(unsigned tag, float v) {
    union { float f; unsigned u; } c; c.f = v;
    return ((unsigned long long)tag << 32) | (unsigned long long)c.u;
}

// Persistent grouped LSTM: 256 WGs = 16 batch-groups x 16 j-slices, 1 WG/CU.
// R6: LDS-issue bottleneck removed. Thread task = (4 rows x 2 batches x
// 32-k chunk); W_ih/W_hh chunks live ONLY in VGPRs (loaded from global at
// init -- no LDS W copy, compiler can't rematerialize). x/h broadcast reads:
// 16 ds_read_b128 per thread per projection (was 128 total). Partials
// reduced via small LDS transpose. Handshake = R4's tagged 64-bit relaxed
// agent atomics (direct spin, no canary), double-buffered by parity.
__global__ __launch_bounds__(256, 1)
void lstm_kernel(const int* __restrict__ sent, const float* __restrict__ emb,
                 const float* __restrict__ W_ih, const float* __restrict__ W_hh,
                 const float* __restrict__ b_ih, const float* __restrict__ b_hh,
                 const float* __restrict__ W_z,
                 unsigned long long* __restrict__ hbuf,
                 float* __restrict__ part)
{
    __shared__ float x_sw[4 * XLD];
    __shared__ float h_sw[4 * XLD];
    __shared__ float red_s[7 * 260 + 256];  // [kc] stride 260, [b]*64, [row]
    __shared__ float g_flat[256];           // gate*64 + b*16 + jj
    __shared__ float c_s[64];               // b*16 + jj
    __shared__ float p_s[64];
    __shared__ int   tok_ns[4];

    const int tid  = threadIdx.x;
    // XCD-clustering swizzle: under round-robin block->XCD dispatch, a
    // group's 16 WGs land on one XCD (2 groups per XCD). Heuristic only.
    const int xcd  = blockIdx.x & 7;
    const int slot = blockIdx.x >> 3;       // 0..31
    const int grp  = xcd * 2 + (slot >> 4); // 0..15 batch group
    const int jgrp = slot & 15;             // 0..15 j-slice
    const int b0   = grp << 2;
    const int j0   = jgrp << 4;

    const int wv    = tid >> 6;
    const int lane  = tid & 63;
    const int rg    = lane >> 2;            // 0..15 row-group (4 rows)
    const int klow  = lane & 3;
    const int kc    = (wv >> 1) * 4 + klow; // 0..7  k-chunk (32 floats)
    const int bp    = wv & 1;               // batch pair
    const int kbase = kc << 5;

    // ---- W chunks -> VGPRs (one-time global read; no LDS copy) ----
    float4 wih_r[32], whh_r[32];
    #pragma unroll
    for (int i = 0; i < 4; ++i) {
        int lr_i = rg * 4 + i;
        long grow = (long)((lr_i >> 4) * HH + j0 + (lr_i & 15));
        const float4* wi = (const float4*)(W_ih + grow * EE + kbase);
        const float4* wh = (const float4*)(W_hh + grow * EE + kbase);
        #pragma unroll
        for (int mi = 0; mi < 8; ++mi) {
            wih_r[i * 8 + mi] = wi[mi];
            whh_r[i * 8 + mi] = wh[mi];
        }
    }

    // reducer mapping: one thread per output (row, batch)
    const int rrow = tid & 63;
    const int rb   = tid >> 6;
    const long grow_r = (long)((rrow >> 4) * HH + j0 + (rrow & 15));
    const float bias_red = b_ih[grow_r] + b_hh[grow_r];
    const int gidx = (rrow >> 4) * 64 + rb * 16 + (rrow & 15);

    float wz_r = 0.f;
    if (tid < 64) {
        c_s[tid] = 0.f;
        wz_r = W_z[j0 + (tid & 15)];
    }
    if (tid < 4) tok_ns[tid] = sent[0 * NB + b0 + tid];
    __syncthreads();
    {   // prologue: stage x for t=0 (swizzled)
        int b  = tid >> 6;
        int e4 = tid & 63;
        float4 xv = ((const float4*)(emb + (long)tok_ns[b] * EE))[e4];
        int phys = 4 * e4 + ((e4 >> 3) << 2);
        *(float4*)(&x_sw[b * XLD + phys]) = xv;
    }
    __syncthreads();

    // consumer fill mapping: this thread loads h[(b0+cb)][cj..cj+3]
    const int cb = tid >> 6;
    const int cj = (tid & 63) << 2;
    const int cphys = cj + ((cj >> 5) << 2);

    for (int t = 0; t < TT; ++t) {
        // ---- phase 1: x partials (x_sw staged previous iteration) ----
        float4 acc4[4][2];
        #pragma unroll
        for (int i = 0; i < 4; ++i)
            #pragma unroll
            for (int j = 0; j < 2; ++j)
                acc4[i][j] = make_float4(0.f, 0.f, 0.f, 0.f);

        #pragma unroll
        for (int j = 0; j < 2; ++j) {
            const float* xb = &x_sw[(2 * bp + j) * XLD + kc * 36];
            #pragma unroll
            for (int mi = 0; mi < 8; ++mi) {
                float4 xv4 = *(const float4*)(xb + mi * 4);
                #pragma unroll
                for (int i = 0; i < 4; ++i) {
                    float4 w = wih_r[i * 8 + mi];
                    acc4[i][j].x += w.x * xv4.x; acc4[i][j].y += w.y * xv4.y;
                    acc4[i][j].z += w.z * xv4.z; acc4[i][j].w += w.w * xv4.w;
                }
            }
        }

        const bool pf = (t + 1 < TT);
        if (tid < 4 && pf) tok_ns[tid] = sent[(t + 1) * NB + b0 + tid];

        // ---- phase 2a: direct tagged spin-load of h_{t-1} (R4 style) ----
        if (t > 0) {
            const unsigned want = (unsigned)t;   // h_{t-1} carries tag t
            unsigned long long* hp =
                hbuf + ((size_t)(((t - 1) & 1) * NB + b0 + cb)) * HH + cj;
            unsigned long long v0, v1, v2, v3;
            v0 = __hip_atomic_load(hp + 0, __ATOMIC_RELAXED, __HIP_MEMORY_SCOPE_AGENT);
            v1 = __hip_atomic_load(hp + 1, __ATOMIC_RELAXED, __HIP_MEMORY_SCOPE_AGENT);
            v2 = __hip_atomic_load(hp + 2, __ATOMIC_RELAXED, __HIP_MEMORY_SCOPE_AGENT);
            v3 = __hip_atomic_load(hp + 3, __ATOMIC_RELAXED, __HIP_MEMORY_SCOPE_AGENT);
            while ((unsigned)(v0 >> 32) != want)
                v0 = __hip_atomic_load(hp + 0, __ATOMIC_RELAXED, __HIP_MEMORY_SCOPE_AGENT);
            while ((unsigned)(v1 >> 32) != want)
                v1 = __hip_atomic_load(hp + 1, __ATOMIC_RELAXED, __HIP_MEMORY_SCOPE_AGENT);
            while ((unsigned)(v2 >> 32) != want)
                v2 = __hip_atomic_load(hp + 2, __ATOMIC_RELAXED, __HIP_MEMORY_SCOPE_AGENT);
            while ((unsigned)(v3 >> 32) != want)
                v3 = __hip_atomic_load(hp + 3, __ATOMIC_RELAXED, __HIP_MEMORY_SCOPE_AGENT);
            union { unsigned u; float f; } c0, c1, c2, c3;
            c0.u = (unsigned)v0; c1.u = (unsigned)v1;
            c2.u = (unsigned)v2; c3.u = (unsigned)v3;
            *(float4*)(&h_sw[cb * XLD + cphys]) =
                make_float4(c0.f, c1.f, c2.f, c3.f);
        }
        __syncthreads();   // B1: h_sw ready; x_sw reads done; tok_ns ready

        float4 xv;         // emb prefetch (completes behind hacc)
        if (pf) {
            int b  = tid >> 6;
            int e4 = tid & 63;
            xv = ((const float4*)(emb + (long)tok_ns[b] * EE))[e4];
        }

        // ---- phase 2b: h partials into same accumulators ----
        if (t > 0) {
            #pragma unroll
            for (int j = 0; j < 2; ++j) {
                const float* hb = &h_sw[(2 * bp + j) * XLD + kc * 36];
                #pragma unroll
                for (int mi = 0; mi < 8; ++mi) {
                    float4 hv4 = *(const float4*)(hb + mi * 4);
                    #pragma unroll
                    for (int i = 0; i < 4; ++i) {
                        float4 w = whh_r[i * 8 + mi];
                        acc4[i][j].x += w.x * hv4.x; acc4[i][j].y += w.y * hv4.y;
                        acc4[i][j].z += w.z * hv4.z; acc4[i][j].w += w.w * hv4.w;
                    }
                }
            }
        }
        // horizontal-add partials, write to reduction scratch
        #pragma unroll
        for (int j = 0; j < 2; ++j) {
            int b = 2 * bp + j;
            float4 v;
            v.x = (acc4[0][j].x + acc4[0][j].y) + (acc4[0][j].z + acc4[0][j].w);
            v.y = (acc4[1][j].x + acc4[1][j].y) + (acc4[1][j].z + acc4[1][j].w);
            v.z = (acc4[2][j].x + acc4[2][j].y) + (acc4[2][j].z + acc4[2][j].w);
            v.w = (acc4[3][j].x + acc4[3][j].y) + (acc4[3][j].z + acc4[3][j].w);
            *(float4*)(&red_s[kc * 260 + b * 64 + rg * 4]) = v;
        }
        if (pf) {          // stage next x (x_sw readers finished pre-B1)
            int b  = tid >> 6;
            int e4 = tid & 63;
            int phys = 4 * e4 + ((e4 >> 3) << 2);
            *(float4*)(&x_sw[b * XLD + phys]) = xv;
        }
        __syncthreads();   // B2: red_s ready; x_sw staged for t+1

        // ---- phase 2c: reduce 8 k-chunk partials -> pre-activation ----
        {
            float s = bias_red;
            #pragma unroll
            for (int k2 = 0; k2 < 8; ++k2)
                s += red_s[k2 * 260 + rb * 64 + rrow];
            g_flat[gidx] = s;
        }
        __syncthreads();   // B3: g_flat ready

        // ---- phase 3: gates + state update + tagged publish ----
        if (tid < 64) {
            int b = tid >> 4, jj = tid & 15;
            float gi = g_flat[0 * 64 + b * 16 + jj];
            float gf = g_flat[1 * 64 + b * 16 + jj];
            float gg = g_flat[2 * 64 + b * 16 + jj];
            float go = g_flat[3 * 64 + b * 16 + jj];
            float c  = c_s[tid];
            float cn = sigf(gf) * c + sigf(gi) * tanhf(gg);
            float hn = sigf(go) * tanhf(cn);
            c_s[tid] = cn;
            p_s[tid] = hn * wz_r;
            __hip_atomic_store(
                hbuf + ((size_t)((t & 1) * NB + b0 + b)) * HH + j0 + jj,
                packh((unsigned)(t + 1), hn),
                __ATOMIC_RELAXED, __HIP_MEMORY_SCOPE_AGENT);
        }
        __syncthreads();   // B4: p_s ready

        if (tid < 4) {     // deterministic pz partial for this (t, jslice, b)
            float s = 0.f;
            #pragma unroll
            for (int jj = 0; jj < JW; ++jj) s += p_s[tid * 16 + jj];
            part[(t * PJ + jgrp) * NB + b0 + tid] = s;
        }
    }
}

__global__ void pz_kernel(const float* __restrict__ part,
                          const float* __restrict__ noise,
                          const float* __restrict__ b_z,
                          float* __restrict__ out)
{
    int idx = blockIdx.x * blockDim.x + threadIdx.x;  // t*64 + b
    if (idx >= TT * NB) return;
    int t = idx >> 6, b = idx & 63;
    float s = b_z[0];
    #pragma unroll
    for (int jg = 0; jg < PJ; ++jg) s += part[(t * PJ + jg) * NB + b];
    float pz = 1.f / (1.f + expf(-s));
    out[idx] = pz;
    out[TT * NB + idx] = (noise[idx] < pz) ? 1.f : 0.f;
}

// One block per batch column: stable compaction of tokens where z==1.
__global__ void compact_kernel(const int* __restrict__ sent,
                               const float* __restrict__ zbuf,
                               float* __restrict__ rat,
                               float* __restrict__ zsz)
{
    __shared__ float rat_s[TT];
    __shared__ int scan_s[256];
    int b = blockIdx.x, tid = threadIdx.x;
    int zloc[8];
    int base = tid * 8;
    int c = 0;
    #pragma unroll
    for (int i = 0; i < 8; ++i) {
        zloc[i] = (zbuf[(base + i) * NB + b] != 0.f) ? 1 : 0;
        c += zloc[i];
    }
    scan_s[tid] = c;
    for (int i = tid; i < TT; i += 256) rat_s[i] = 0.f;
    __syncthreads();
    for (int off = 1; off < 256; off <<= 1) {
        int v = scan_s[tid];
        int add = (tid >= off) ? scan_s[tid - off] : 0;
        __syncthreads();
        scan_s[tid] = v + add;
        __syncthreads();
    }
    int total = scan_s[255];
    int pos = scan_s[tid] - c;  // exclusive prefix
    #pragma unroll
    for (int i = 0; i < 8; ++i) {
        if (zloc[i]) { rat_s[pos] = (float)sent[(base + i) * NB + b]; ++pos; }
    }
    __syncthreads();
    for (int i = tid; i < TT; i += 256) rat[i * NB + b] = rat_s[i];
    if (tid == 0) zsz[b] = (float)total;
}

extern "C" void kernel_launch(void* const* d_in, const int* in_sizes, int n_in,
                              void* d_out, int out_size, void* d_ws, size_t ws_size,
                              hipStream_t stream)
{
    const int*   sent  = (const int*)d_in[0];
    const float* noise = (const float*)d_in[1];
    const float* emb   = (const float*)d_in[2];
    const float* W_ih  = (const float*)d_in[3];
    const float* W_hh  = (const float*)d_in[4];
    const float* b_ih  = (const float*)d_in[5];
    const float* b_hh  = (const float*)d_in[6];
    const float* W_z   = (const float*)d_in[7];
    const float* b_z   = (const float*)d_in[8];
    float* out = (float*)d_out;

    char* ws = (char*)d_ws;
    unsigned long long* hbuf = (unsigned long long*)ws;     // 2*64*256*8 = 256 KB
    float* part = (float*)(ws + 262144);                    // 2048*16*64*4 = 8 MB

    // tags must start != any expected tag (1..2048)
    hipMemsetAsync(hbuf, 0, 2 * NB * HH * sizeof(unsigned long long), stream);

    lstm_kernel<<<256, 256, 0, stream>>>(sent, emb, W_ih, W_hh, b_ih, b_hh, W_z,
                                         hbuf, part);
    pz_kernel<<<(TT * NB) / 256, 256, 0, stream>>>(part, noise, b_z, out);
    compact_kernel<<<NB, 256, 0, stream>>>(sent, out + TT * NB,
                                           out + 2 * TT * NB, out + 3 * TT * NB);
}